// Round 13
// baseline (188.102 us; speedup 1.0000x reference)
//
#include <hip/hip_runtime.h>
#include <hip/hip_fp16.h>
#include <stdint.h>

// Problem constants
#define HIDDEN 1024
#define HEADS  16
#define DH     64
#define B_     2
#define L_     2048
#define M_TOT  (B_ * L_)          // 4096
#define ELEMS  (M_TOT * HIDDEN)   // 4,194,304
#define LOG2E  1.44269504088896340736f

typedef _Float16 f16;
typedef _Float16 f16x4 __attribute__((ext_vector_type(4)));
typedef _Float16 f16x8 __attribute__((ext_vector_type(8)));
typedef float    f32x4 __attribute__((ext_vector_type(4)));
typedef uint32_t u32;
typedef __attribute__((address_space(1))) u32 gu32;   // global ptr for global_load_lds
typedef __attribute__((address_space(3))) u32 su32;   // LDS ptr for global_load_lds

#define MFMA32(a, b, c) __builtin_amdgcn_mfma_f32_16x16x32_f16(a, b, c, 0, 0, 0)

// ---------------------------------------------------------------------------
// r22: r12 base (187.3 µs, reproduced optimum) + proj_out retile.
// proj_out was the last untouched kernel: 128x64 tile, grid 512 = 2 blk/CU
// = 8 waves/CU — the same latency-starved regime that cost attn in r1/r3.
// Retile to 64x64, grid 1024 (1D, XCD-chunked): 4 blk/CU x 4 waves =
// 16 waves/CU, LDS 24 KB. Per-CU MFMA work unchanged; 2x latency hiding.
// XCD swizzle: lb=(bid&7)*128+(bid>>3) bijective (1024%8==0); decompose
// nbi=lb&15, mbi=lb>>4 -> each XCD owns 8 mb-tiles x all nb: working set
// A 1 MB + Wo 2 MB = 3 MB < 4 MB L2.
// Session ledger: r7/r12 = 187-189 optimum; r8/r9 (VGPR-cap cliffs),
// r10 (V-from-L2 vmcnt mixing), r11 (same-iter reg-staged cvt) refuted.
// Rules: (1) never force VGPR cap at the boundary; 512-thr blocks take
// only 2/4/6/8 as launch_bounds arg2. (2) never mix per-lane global loads
// with global_load_lds in a pipelined loop. (3) reg-staged operands under
// a per-iter barrier need >=2-tile depth. attn closed at 44 µs.
// ---------------------------------------------------------------------------
// mfma layouts (verified):
//  16x16x32: A[m=lane&15][k=quad*8+j] (8 f16), B[k=quad*8+j][n=lane&15],
//            C/D row=quad*4+reg, col=lane&15
//  A and B operands have IDENTICAL per-lane structure -> swapping operand
//  order computes C^T for free: (a) attn's S^T/P^T register chain;
//  (b) GEMM epilogue coalescing — SWAP=true -> vector stores.
//  attn v4: KVBLK=128 as 2x64-key sub-tiles (gi) with verified
//  conflict-free swizzles; key-PERMUTED S^T tiles put exp2(S^T) directly
//  into the MFMA32 B-operand layout — PV + denominator colsum all 16x16x32.
// ---------------------------------------------------------------------------

// ---------------- f32 -> f16 pre-convert; weights packed [Wq;Wk;Wv;Wo] -----
__global__ __launch_bounds__(256)
void convert_f16(const float* __restrict__ query,
                 const float* __restrict__ Wq, const float* __restrict__ Wk,
                 const float* __restrict__ Wv, const float* __restrict__ Wo,
                 f16* __restrict__ Qh, f16* __restrict__ Wh)
{
    const int NQ4 = ELEMS / 4;              // 1048576 float4 units
    const int NW4 = (HIDDEN * HIDDEN) / 4;  // 262144 per weight
    const int total = NQ4 + 4 * NW4;
    for (int u = blockIdx.x * 256 + threadIdx.x; u < total; u += gridDim.x * 256) {
        float4 v; f16* dp;
        if (u < NQ4) {
            v = ((const float4*)query)[u];
            dp = Qh + (size_t)u * 4;
        } else {
            const int u2 = u - NQ4;
            const int w = u2 >> 18;            // NW4 = 2^18
            const int off = u2 & (NW4 - 1);
            const float* W = (w == 0) ? Wq : (w == 1) ? Wk : (w == 2) ? Wv : Wo;
            v = ((const float4*)W)[off];
            dp = Wh + (size_t)u2 * 4;          // stacked rows: q,k,v,o
        }
        f16x4 h = { (f16)v.x, (f16)v.y, (f16)v.z, (f16)v.w };
        *(f16x4*)dp = h;
    }
}

// ---------------- shared GEMM main loop: ring-3, counted vmcnt -------------
// LDS from the kernel's dynamic shared block (aliased across instantiations).
// SWAP=false: acc[i][j] = C[m][n]; SWAP=true: acc[i][j] = C^T.
// Wait formula: L = AISS+BISS loads/iter; vmcnt(L) at iter top leaves tile
// t+1's loads in flight while guaranteeing tile t resident.
template<int TM, int TN, bool SWAP>
__device__ __forceinline__
void gemm_loop(const f16* __restrict__ A, const f16* __restrict__ W,
               int mb, int nb, f32x4 (&acc)[TM / 32][TN / 32])
{
    extern __shared__ f16 smem[];            // 3*(TM+TN)*32 f16
    f16* As = smem;                          // [3][TM*32]
    f16* Bs = smem + 3 * TM * 32;            // [3][TN*32]

    const int tid  = threadIdx.x;
    const int lane = tid & 63;
    const int wave = tid >> 6;
    const int quad = lane >> 4;
    const int l16  = lane & 15;
    const int wm   = (wave >> 1) * (TM / 2);
    const int wn   = (wave & 1) * (TN / 2);

    constexpr int AISS = TM / 64;
    constexpr int BISS = TN / 64;
    int aoff[AISS], boff[BISS];
#pragma unroll
    for (int q = 0; q < AISS; q++) {
        const int p16 = (wave * AISS + q) * 64 + lane;
        const int r = p16 >> 2;
        const int c8 = (p16 & 3) ^ ((r >> 1) & 3);
        aoff[q] = (mb + r) * HIDDEN + c8 * 8;
    }
#pragma unroll
    for (int q = 0; q < BISS; q++) {
        const int p16 = (wave * BISS + q) * 64 + lane;
        const int r = p16 >> 2;
        const int c8 = (p16 & 3) ^ ((r >> 1) & 3);
        boff[q] = (nb + r) * HIDDEN + c8 * 8;
    }

    // prologue: stage tiles 0,1 into slots 0,1
#pragma unroll
    for (int p = 0; p < 2; p++) {
#pragma unroll
        for (int q = 0; q < AISS; q++)
            __builtin_amdgcn_global_load_lds((gu32*)&A[aoff[q] + p * 32],
                                             (su32*)&As[p * TM * 32 + (wave * AISS + q) * 512], 16, 0, 0);
#pragma unroll
        for (int q = 0; q < BISS; q++)
            __builtin_amdgcn_global_load_lds((gu32*)&W[boff[q] + p * 32],
                                             (su32*)&Bs[p * TN * 32 + (wave * BISS + q) * 512], 16, 0, 0);
    }

    int sl = 0;                                  // slot holding tile t
#pragma unroll 1
    for (int kb = 0; kb < HIDDEN; kb += 32) {
        // all but the newest LOADS (= tile t+1) retired -> tile t resident
        if constexpr (AISS + BISS == 4)
            asm volatile("s_waitcnt vmcnt(4)" ::: "memory");
        else if constexpr (AISS + BISS == 3)
            asm volatile("s_waitcnt vmcnt(3)" ::: "memory");
        else
            asm volatile("s_waitcnt vmcnt(2)" ::: "memory");
        __builtin_amdgcn_s_barrier();            // publish tile t block-wide
        __builtin_amdgcn_sched_barrier(0);       // no motion across barrier

        // issue tile t+2 into slot (t+2)%3 == (t-1)%3 (wrap-to-0 harmless)
        const int nkb = (kb + 64 < HIDDEN) ? kb + 64 : 0;
        const int si  = (sl >= 1) ? sl - 1 : 2;
#pragma unroll
        for (int q = 0; q < AISS; q++)
            __builtin_amdgcn_global_load_lds((gu32*)&A[aoff[q] + nkb],
                                             (su32*)&As[si * TM * 32 + (wave * AISS + q) * 512], 16, 0, 0);
#pragma unroll
        for (int q = 0; q < BISS; q++)
            __builtin_amdgcn_global_load_lds((gu32*)&W[boff[q] + nkb],
                                             (su32*)&Bs[si * TN * 32 + (wave * BISS + q) * 512], 16, 0, 0);

        f16x8 af[TM / 32], bf[TN / 32];
#pragma unroll
        for (int i = 0; i < TM / 32; i++) {
            const int r = wm + i * 16 + l16;
            af[i] = *(const f16x8*)&As[sl * TM * 32 + r * 32 + (quad ^ ((r >> 1) & 3)) * 8];
        }
#pragma unroll
        for (int j = 0; j < TN / 32; j++) {
            const int r = wn + j * 16 + l16;
            bf[j] = *(const f16x8*)&Bs[sl * TN * 32 + r * 32 + (quad ^ ((r >> 1) & 3)) * 8];
        }
#pragma unroll
        for (int i = 0; i < TM / 32; i++)
#pragma unroll
            for (int j = 0; j < TN / 32; j++) {
                if constexpr (SWAP)
                    acc[i][j] = MFMA32(bf[j], af[i], acc[i][j]);
                else
                    acc[i][j] = MFMA32(af[i], bf[j], acc[i][j]);
            }

        sl = (sl + 1 == 3) ? 0 : sl + 1;
    }
    // drain wrap staging; epilogue only reads acc (no LDS reuse)
    asm volatile("s_waitcnt vmcnt(0)" ::: "memory");
}

// QKV projection: A = query f16 [4096][1024], W = packed [Wq;Wk;Wv] rows.
// Q/K blocks run SWAP=true -> lanes hold 4 consecutive dd -> f16x4 stores.
// V blocks run SWAP=false (V^T layout wants 4 consecutive l per lane).
__global__ __launch_bounds__(256)
void proj_qkv(const f16* __restrict__ A, const f16* __restrict__ W,
              const float* __restrict__ bq, const float* __restrict__ bk,
              const float* __restrict__ bv,
              f16* __restrict__ Qo, f16* __restrict__ Ko, f16* __restrict__ Vo)
{
    f32x4 acc[4][4] = {};
    const int mb = blockIdx.x * 128, nb = blockIdx.y * 128;
    const int nsel = nb >> 10;
    if (nsel < 2) gemm_loop<128, 128, true >(A, W, mb, nb, acc);
    else          gemm_loop<128, 128, false>(A, W, mb, nb, acc);

    const int lane = threadIdx.x & 63, wave = threadIdx.x >> 6;
    const int quad = lane >> 4, l16 = lane & 15;
    const int wm = (wave >> 1) * 64, wn = (wave & 1) * 64;
    const int nbase = nb & 1023;

    if (nsel < 2) {
        const float* bias = nsel ? bk : bq;
        f16* out = nsel ? Ko : Qo;
        const float scale = nsel ? 1.0f : 0.125f * LOG2E;
#pragma unroll
        for (int i = 0; i < 4; i++) {
            const int m = mb + wm + i * 16 + l16;        // SWAP: col = m
            const int b = m >> 11, l = m & (L_ - 1);
#pragma unroll
            for (int j = 0; j < 4; j++) {
                const int n0 = nbase + wn + j * 16 + quad * 4;   // SWAP: row = n
                const f32x4 bl4 = *(const f32x4*)&bias[n0];
                const int h = n0 >> 6, dd = n0 & 63;
                f16x4 pk;
#pragma unroll
                for (int r = 0; r < 4; r++)
                    pk[r] = (f16)((acc[i][j][r] + bl4[r]) * scale);
                *(f16x4*)&out[(((b * HEADS + h) * L_) + l) * DH + dd] = pk;
            }
        }
    } else {
#pragma unroll
        for (int i = 0; i < 4; i++)
#pragma unroll
            for (int j = 0; j < 4; j++) {
                const int n1 = nbase + wn + j * 16 + l16;
                const float bn = bv[n1];
                const int h = n1 >> 6, dd = n1 & 63;
                const int m0 = mb + wm + i * 16 + quad * 4;
                const int b = m0 >> 11, l0 = m0 & (L_ - 1);
                f16x4 pk;
#pragma unroll
                for (int r = 0; r < 4; r++) pk[r] = (f16)(acc[i][j][r] + bn);
                *(f16x4*)&Vo[((size_t)(b * HEADS + h) * DH + dd) * L_ + l0] = pk;
            }
    }
}

// Output projection: 64x64 tile, grid 1024 (1D, XCD-chunked) = 4 blk/CU,
// 16 waves/CU (was 128x64 / grid 512 / 2 blk/CU — latency-starved).
// SWAP=true -> float4 stores (16 rows x 64B contiguous per instruction).
__global__ __launch_bounds__(256)
void proj_out(const f16* __restrict__ A, const f16* __restrict__ W,
              const float* __restrict__ bo, float* __restrict__ out)
{
    f32x4 acc[2][2] = {};
    const int bid = (int)blockIdx.x;
    const int lb  = (bid & 7) * 128 + (bid >> 3);  // bijective XCD swizzle
    const int mb  = (lb >> 4) * 64;                // 64 m-tiles
    const int nb  = (lb & 15) * 64;                // 16 n-tiles
    gemm_loop<64, 64, true>(A, W, mb, nb, acc);

    const int lane = threadIdx.x & 63, wave = threadIdx.x >> 6;
    const int quad = lane >> 4, l16 = lane & 15;
    const int wm = (wave >> 1) * 32, wn = (wave & 1) * 32;
#pragma unroll
    for (int i = 0; i < 2; i++) {
        const int m = mb + wm + i * 16 + l16;            // SWAP: col = m
#pragma unroll
        for (int j = 0; j < 2; j++) {
            const int n0 = nb + wn + j * 16 + quad * 4;  // SWAP: row = n
            const float4 b4 = *(const float4*)&bo[n0];
            float4 st;
            st.x = acc[i][j][0] + b4.x;
            st.y = acc[i][j][1] + b4.y;
            st.z = acc[i][j][2] + b4.z;
            st.w = acc[i][j][3] + b4.w;
            *(float4*)&out[m * HIDDEN + n0] = st;
        }
    }
}

// ---------------- flash attention v4: qt=2 + key-split, KVBLK=128 ----------
// Block = 512 threads = 8 waves; 128 Q-rows/block; grid 512 (2 blk/CU,
// LDS 72 KB). Wave w: Q-group qg=w>>1 (rows qg*32..+31), key-half g=w&1.
// Each 128-key iteration = 2 sub-tiles (gi) of 64 keys with the verified
// [64][64] conflict-free layouts. Per wave per iter: 16 ds_read, 36 MFMA32,
// 32 exp2, 4 gload_lds, 2 barriers.
// End: key-half pairs sum partial O/osum through the dead K/V LDS buffers.
// XCD swizzle bijective (512%8==0). No-max softmax in exp2 domain.
__global__ __launch_bounds__(512, 4)
void attn(const f16* __restrict__ Q, const f16* __restrict__ K,
          const f16* __restrict__ Vt, const float* __restrict__ bias,
          f16* __restrict__ X)
{
    __shared__ f16 Ks[2][2][64 * 64];  // [buf][gi][key][dd]  8 KB each = 32 KB
    __shared__ f16 Vs[2][2][64 * 64];  // [buf][gi][dd][key]  8 KB each = 32 KB
    __shared__ float biasl[L_];        // bias * log2e        8 KB

    const int tid  = threadIdx.x;
    const int lane = tid & 63;
    const int wave = tid >> 6;         // 0..7
    const int quad = lane >> 4;
    const int l16  = lane & 15;
    const int qg   = wave >> 1;        // Q-row group 0..3
    const int g    = wave & 1;         // key-half 0..1 (within each 64-key gi)

    const int bid = (int)blockIdx.x;
    const int lb  = (bid & 7) * 64 + (bid >> 3);   // XCD-contiguous, bijective
    const int bh  = lb >> 4;                       // 0..31
    const int b   = bh >> 4, h = bh & 15;
    const int qrow0 = (lb & 15) * 128 + qg * 32;

    const f16* Qh  = Q  + (size_t)bh * L_ * DH;
    const f16* Kh  = K  + (size_t)bh * L_ * DH;
    const f16* Vth = Vt + (size_t)bh * DH * L_;

    {   // stage bias * log2e: 512 float4 units, exactly one per thread
        const float4 v = ((const float4*)(bias + b * L_))[tid];
        biasl[tid * 4 + 0] = v.x * LOG2E;
        biasl[tid * 4 + 1] = v.y * LOG2E;
        biasl[tid * 4 + 2] = v.z * LOG2E;
        biasl[tid * 4 + 3] = v.w * LOG2E;
    }

    // staging geometry (per 64-key sub-tile):
    // unit p = wave*64 + lane; row r = p>>3, w8 = p&7
    // K source unit = w8 ^ (r&7) ^ (((r>>3)&1)<<2); V source unit = w8 ^ (r&7)
    int krow, kcol, vcol;
    {
        const int p = wave * 64 + lane;
        const int r = p >> 3;
        const int w8 = p & 7;
        krow = r;
        kcol = (w8 ^ (r & 7) ^ (((r >> 3) & 1) << 2)) * 8;
        vcol = (w8 ^ (r & 7)) * 8;
    }

    // Q fragments (B operand of S^T): qf[qtile][dd-half]
    f16x8 qf[2][2];
#pragma unroll
    for (int qt = 0; qt < 2; qt++)
#pragma unroll
        for (int hh = 0; hh < 2; hh++)
            qf[qt][hh] = *(const f16x8*)&Qh[(qrow0 + qt * 16 + l16) * DH + hh * 32 + quad * 8];

    // LDS read offsets for this wave's fixed key-half g (within a sub-tile):
    // tile X rows rX = g*32 + (l16>>2)*8 + (l16&3); tile Y = rX+4.
    int koffX[2], koffY[2], voff[4];
    {
        const int rX = g * 32 + ((l16 >> 2) << 3) + (l16 & 3);
        const int rY = rX + 4;
        const int gkX = (rX & 7) ^ (((rX >> 3) & 1) << 2);
        const int gkY = (rY & 7) ^ (((rY >> 3) & 1) << 2);
#pragma unroll
        for (int hh = 0; hh < 2; hh++) {
            koffX[hh] = rX * 64 + (((hh * 4 + quad) ^ gkX) << 3);
            koffY[hh] = rY * 64 + (((hh * 4 + quad) ^ gkY) << 3);
        }
#pragma unroll
        for (int t = 0; t < 4; t++) {
            const int vr = t * 16 + l16;
            voff[t] = vr * 64 + (((g * 4 + quad) ^ (vr & 7)) << 3);
        }
    }

    // prologue: stage 128-key tile kb=0 into buf 0 (2 K + 2 V loads per wave)
#pragma unroll
    for (int gi = 0; gi < 2; gi++) {
        __builtin_amdgcn_global_load_lds(
            (gu32*)(Kh + (size_t)(gi * 64 + krow) * DH + kcol),
            (su32*)&Ks[0][gi][wave * 512], 16, 0, 0);
        __builtin_amdgcn_global_load_lds(
            (gu32*)(Vth + (size_t)krow * L_ + gi * 64 + vcol),
            (su32*)&Vs[0][gi][wave * 512], 16, 0, 0);
    }

    f32x4 o[2][4] = {};      // partial O^T (this key-half): [qtile][ddtile]
    f32x4 osum[2] = {};      // partial softmax denominator
    const f16x8 ones8 = { (f16)1.f, (f16)1.f, (f16)1.f, (f16)1.f,
                          (f16)1.f, (f16)1.f, (f16)1.f, (f16)1.f };
    __syncthreads();         // drains prologue staging + biasl

#pragma unroll 1
    for (int kb = 0; kb < L_; kb += 128) {
        const int buf = (kb >> 7) & 1;
        const int nkb = (kb + 128 < L_) ? kb + 128 : 0;   // last prefetch harmless

        // prefetch next 128-key tile into buf^1 (async, drained by end barrier)
#pragma unroll
        for (int gi = 0; gi < 2; gi++) {
            __builtin_amdgcn_global_load_lds(
                (gu32*)(Kh + (size_t)(nkb + gi * 64 + krow) * DH + kcol),
                (su32*)&Ks[buf ^ 1][gi][wave * 512], 16, 0, 0);
            __builtin_amdgcn_global_load_lds(
                (gu32*)(Vth + (size_t)krow * L_ + nkb + gi * 64 + vcol),
                (su32*)&Vs[buf ^ 1][gi][wave * 512], 16, 0, 0);
        }

        // two independent 64-key sub-tiles; this wave's key-half of each
#pragma unroll
        for (int gi = 0; gi < 2; gi++) {
            const f16* Kb = &Ks[buf][gi][0];
            const f16* Vb = &Vs[buf][gi][0];
            const f16x8 kx0 = *(const f16x8*)&Kb[koffX[0]];
            const f16x8 kx1 = *(const f16x8*)&Kb[koffX[1]];
            const f16x8 ky0 = *(const f16x8*)&Kb[koffY[0]];
            const f16x8 ky1 = *(const f16x8*)&Kb[koffY[1]];
            f16x8 va[4];
#pragma unroll
            for (int t = 0; t < 4; t++)
                va[t] = *(const f16x8*)&Vb[voff[t]];
            const f32x4 blvX = *(const f32x4*)&biasl[kb + gi * 64 + g * 32 + quad * 8];
            const f32x4 blvY = *(const f32x4*)&biasl[kb + gi * 64 + g * 32 + quad * 8 + 4];

#pragma unroll
            for (int qt = 0; qt < 2; qt++) {
                f32x4 zx = blvX, zy = blvY;      // C = bias (per permuted key-row)
                zx = MFMA32(kx0, qf[qt][0], zx);
                zx = MFMA32(kx1, qf[qt][1], zx); // S^T[key=..+quad*8+r][q]+bias
                zy = MFMA32(ky0, qf[qt][0], zy);
                zy = MFMA32(ky1, qf[qt][1], zy); // S^T[key=..+quad*8+4+r][q]+bias
                const f16x8 pb = {
                    (f16)__builtin_amdgcn_exp2f(zx[0]), (f16)__builtin_amdgcn_exp2f(zx[1]),
                    (f16)__builtin_amdgcn_exp2f(zx[2]), (f16)__builtin_amdgcn_exp2f(zx[3]),
                    (f16)__builtin_amdgcn_exp2f(zy[0]), (f16)__builtin_amdgcn_exp2f(zy[1]),
                    (f16)__builtin_amdgcn_exp2f(zy[2]), (f16)__builtin_amdgcn_exp2f(zy[3]) };
                // P^T B-frag: k=quad*8+j over this wave's 32 keys of sub-tile gi
#pragma unroll
                for (int t = 0; t < 4; t++)
                    o[qt][t] = MFMA32(va[t], pb, o[qt][t]);
                osum[qt] = MFMA32(ones8, pb, osum[qt]);   // denominator colsum
            }
        }
        __syncthreads();   // staged tile ready; reads of buf done
    }
    // (final __syncthreads drained the wrap prefetch -> K/V LDS is dead)

    // cross-wave reduction: key-half g=1 publishes partials via dead LDS.
    float* o0 = (float*)Ks;
    float* o1 = (float*)Vs;
    if (g) {
#pragma unroll
        for (int t = 0; t < 4; t++)
#pragma unroll
            for (int r = 0; r < 4; r++) {
                o0[(qg * 16 + t * 4 + r) * 64 + lane] = o[0][t][r];
                o1[(qg * 16 + t * 4 + r) * 64 + lane] = o[1][t][r];
            }
        biasl[(qg * 64 + lane) * 2 + 0] = osum[0][0];
        biasl[(qg * 64 + lane) * 2 + 1] = osum[1][0];
    }
    __syncthreads();
    if (!g) {
#pragma unroll
        for (int t = 0; t < 4; t++)
#pragma unroll
            for (int r = 0; r < 4; r++) {
                o[0][t][r] += o0[(qg * 16 + t * 4 + r) * 64 + lane];
                o[1][t][r] += o1[(qg * 16 + t * 4 + r) * 64 + lane];
            }
        const float s0 = osum[0][0] + biasl[(qg * 64 + lane) * 2 + 0];
        const float s1 = osum[1][0] + biasl[(qg * 64 + lane) * 2 + 1];
#pragma unroll
        for (int qt = 0; qt < 2; qt++) {
            const float inv = 1.0f / (qt ? s1 : s0);
            const size_t qrow = (size_t)b * L_ + qrow0 + qt * 16 + l16;
#pragma unroll
            for (int t = 0; t < 4; t++) {
                f16x4 pk;
#pragma unroll
                for (int r = 0; r < 4; r++) pk[r] = (f16)(o[qt][t][r] * inv);
                *(f16x4*)&X[qrow * HIDDEN + h * DH + t * 16 + quad * 4] = pk;
            }
        }
    }
}

extern "C" void kernel_launch(void* const* d_in, const int* in_sizes, int n_in,
                              void* d_out, int out_size, void* d_ws, size_t ws_size,
                              hipStream_t stream)
{
    const float* query = (const float*)d_in[0];
    const float* bias  = (const float*)d_in[1];
    const float* Wq = (const float*)d_in[2]; const float* bq = (const float*)d_in[3];
    const float* Wk = (const float*)d_in[4]; const float* bk = (const float*)d_in[5];
    const float* Wv = (const float*)d_in[6]; const float* bv = (const float*)d_in[7];
    const float* Wo = (const float*)d_in[8]; const float* bo = (const float*)d_in[9];
    float* out = (float*)d_out;

    // workspace layout (40 MiB):
    f16* Wh = (f16*)d_ws;           // [4096][1024] packed f16 weights (q,k,v,o rows)
    f16* Qh = Wh + 4096 * 1024;     // [4096][1024] query f16; reused as Xf after qkv
    f16* Kf = Qh + ELEMS;           // [B,H,L,64]
    f16* Vf = Kf + ELEMS;           // [B,H,64,L] transposed
    f16* Qf = Vf + ELEMS;           // [B,H,L,64] scaled
    f16* Xf = Qh;                   // alias: query f16 dead after proj_qkv

    convert_f16<<<2048, 256, 0, stream>>>(query, Wq, Wk, Wv, Wo, Qh, Wh);
    // dynamic LDS: 3*(TM+TN)*32 f16 = 3*(128+128)*32*2 = 49152 B
    proj_qkv<<<dim3(32, 24), 256, 49152, stream>>>(Qh, Wh, bq, bk, bv, Qf, Kf, Vf);
    attn<<<512, 512, 0, stream>>>(Qf, Kf, Vf, bias, Xf);
    // 3*(64+64)*32*2 = 24576 B
    proj_out<<<1024, 256, 24576, stream>>>(Xf, Wh + 3072 * 1024, bo, out);
}